// Round 13
// baseline (4737.472 us; speedup 1.0000x reference)
//
#include <hip/hip_runtime.h>

// LSTM (bias-free) T=512, B=512, D=8, H=256 + per-step Linear(H,2).
// R13 (= R12 resubmit; never ran): register-resident weights. 256 blocks x 1024
// threads (ALL CUs), 2 rows/block. Thread (u, q=t>>8) owns k-quarter q (32 k2).
// HALF its fp16 weight slice (16 uint4 = 64 VGPR) lives in registers across ALL
// steps; other half streams from L2 -> per-CU weight traffic 512KB -> 256KB/step.
// Gate GEMM via v_dot2_f32_f16 (fp32 acc). h fp32 (h2s) + fp16 shadow (h16).
// Partials LDS [q][gate][row][u] (32KB); 2 barriers/step.

#define T_STEPS 512
#define B_ROWS  512
#define D_IN    8
#define HID     256

typedef _Float16 half2_t __attribute__((ext_vector_type(2)));

#if defined(__has_builtin)
#  if __has_builtin(__builtin_amdgcn_fdot2)
#    define HAVE_FDOT2 1
#  endif
#endif
#ifndef HAVE_FDOT2
#  define HAVE_FDOT2 0
#endif

#define PW2_ENTRIES (128 * HID)            // 32768 uint4 (16B each) = 512 KB
#define PWIH_FLOATS (4 * HID * D_IN)       // 8192 floats = 32 KB
#define WS_BYTES_NEEDED ((size_t)PW2_ENTRIES * 16 + (size_t)PWIH_FLOATS * 4)

// PW2[k2*HID+u] = uint4{ half2(Whh[g*H+u][2k2], Whh[g*H+u][2k2+1]) : g=0..3 }
// PWih[d*1024 + u*4 + g] = Wih[g*H+u][d]   (fp32, tiny)
__global__ void prep_kernel(const float* __restrict__ Wih,
                            const float* __restrict__ Whh,
                            uint4* __restrict__ PW2,
                            float* __restrict__ PWih) {
  int p = blockIdx.x * 256 + threadIdx.x;
  if (p < PW2_ENTRIES) {
    int u = p & (HID - 1), k2 = p >> 8;
    unsigned int g[4];
    #pragma unroll
    for (int gi = 0; gi < 4; ++gi) {
      float lo = Whh[(gi * HID + u) * HID + 2 * k2];
      float hi = Whh[(gi * HID + u) * HID + 2 * k2 + 1];
      half2_t hv;
      hv[0] = (_Float16)lo;
      hv[1] = (_Float16)hi;
      g[gi] = __builtin_bit_cast(unsigned int, hv);
    }
    PW2[p] = make_uint4(g[0], g[1], g[2], g[3]);
  } else {
    int q = p - PW2_ENTRIES;
    if (q < PWIH_FLOATS) {
      int gg = q & 3, u = (q >> 2) & (HID - 1), d = q >> 10;
      PWih[q] = Wih[(gg * HID + u) * D_IN + d];
    }
  }
}

__device__ __forceinline__ float sigmoidf_(float x) {
  return 1.f / (1.f + expf(-x));
}
__device__ __forceinline__ float tanhf_(float x) {
  float e = expf(2.f * x);
  return 1.f - 2.f / (e + 1.f);
}

__device__ __forceinline__ float dot2f(unsigned int wbits, unsigned int hbits, float acc) {
  half2_t w = __builtin_bit_cast(half2_t, wbits);
  half2_t h = __builtin_bit_cast(half2_t, hbits);
#if HAVE_FDOT2
  return __builtin_amdgcn_fdot2(w, h, acc, false);
#else
  acc = fmaf((float)w[0], (float)h[0], acc);
  return fmaf((float)w[1], (float)h[1], acc);
#endif
}

template <bool DIRECT>
__global__ __launch_bounds__(1024, 4)
void lstm_kernel(const float* __restrict__ hist,
                 const float* __restrict__ Wih,
                 const float* __restrict__ Whh,
                 const float* __restrict__ Wout,
                 const float* __restrict__ bout,
                 const uint4* __restrict__ PW2,
                 const float4* __restrict__ PWih,
                 float* __restrict__ out) {
  __shared__ float2   h2s[HID];             // fp32 h, [u]{row0,row1}, 2KB
  __shared__ _Float16 h16[HID / 2][2][2];   // fp16 h, [k2][row][half], 1KB
  __shared__ float    wo[2 * HID];          // W_out staged, 2KB
  __shared__ float    part[4][4][2][HID];   // [q][gate][row][u] partials, 32KB

  const int t = threadIdx.x;
  const int u = t & (HID - 1);
  const int q = t >> 8;                     // k-quarter 0..3; q<2 also owns row q

  if (t < 2 * HID) wo[t] = Wout[t];
  if (t < HID) h2s[t] = make_float2(0.f, 0.f);
  if (t < 2 * HID) ((_Float16*)h16)[t] = (_Float16)0.f;   // 512 halves total
  float c_reg = 0.f, h_reg = 0.f;
  const float b0 = bout[0], b1 = bout[1];
  __syncthreads();

  const int row0 = blockIdx.x * 2;
  const float4* __restrict__ xp0 = (const float4*)(hist + (long)(row0 + 0) * T_STEPS * D_IN);
  const float4* __restrict__ xp1 = (const float4*)(hist + (long)(row0 + 1) * T_STEPS * D_IN);
  // This thread's weight slice: k2 in [32q, 32q+32); first 16 k2 -> REGISTERS, rest stream.
  const uint4* __restrict__ pwq = DIRECT ? nullptr : (PW2 + (size_t)(32 * q) * HID + u);
  const uint2* __restrict__ h16q = (const uint2*)h16;   // [k2] -> {row0 pair, row1 pair}

  uint4 wreg[16];
  if (!DIRECT) {
    #pragma unroll
    for (int j = 0; j < 16; ++j) wreg[j] = pwq[(size_t)j * HID];
  }
  const uint4* __restrict__ pws = DIRECT ? nullptr : (pwq + (size_t)16 * HID);

  for (int step = 0; step < T_STEPS; ++step) {
    float ai0 = 0.f, ai1 = 0.f;
    float af0 = 0.f, af1 = 0.f;
    float ag0 = 0.f, ag1 = 0.f;
    float ao0 = 0.f, ao1 = 0.f;

    // ---- x @ W_ih.T (D=8, fp32): q==0 waves only, both rows ----
    if (q == 0) {
      float4 a0 = xp0[2 * step], bb0 = xp0[2 * step + 1];
      float4 a1 = xp1[2 * step], bb1 = xp1[2 * step + 1];
      float x0[D_IN] = {a0.x, a0.y, a0.z, a0.w, bb0.x, bb0.y, bb0.z, bb0.w};
      float x1[D_IN] = {a1.x, a1.y, a1.z, a1.w, bb1.x, bb1.y, bb1.z, bb1.w};
      #pragma unroll
      for (int d = 0; d < D_IN; ++d) {
        float4 w;
        if (DIRECT) {
          w.x = Wih[(0 * HID + u) * D_IN + d];
          w.y = Wih[(1 * HID + u) * D_IN + d];
          w.z = Wih[(2 * HID + u) * D_IN + d];
          w.w = Wih[(3 * HID + u) * D_IN + d];
        } else {
          w = PWih[d * HID + u];
        }
        ai0 = fmaf(w.x, x0[d], ai0); af0 = fmaf(w.y, x0[d], af0);
        ag0 = fmaf(w.z, x0[d], ag0); ao0 = fmaf(w.w, x0[d], ao0);
        ai1 = fmaf(w.x, x1[d], ai1); af1 = fmaf(w.y, x1[d], af1);
        ag1 = fmaf(w.z, x1[d], ag1); ao1 = fmaf(w.w, x1[d], ao1);
      }
    }

    // ---- h @ W_hh.T over k-quarter q ----
    if (DIRECT) {
      #pragma unroll 8
      for (int kk = 0; kk < 32; ++kk) {
        int k = 2 * (32 * q + kk);
        float wiA = Whh[(0 * HID + u) * HID + k], wiB = Whh[(0 * HID + u) * HID + k + 1];
        float wfA = Whh[(1 * HID + u) * HID + k], wfB = Whh[(1 * HID + u) * HID + k + 1];
        float wgA = Whh[(2 * HID + u) * HID + k], wgB = Whh[(2 * HID + u) * HID + k + 1];
        float woA = Whh[(3 * HID + u) * HID + k], woB = Whh[(3 * HID + u) * HID + k + 1];
        float2 hA = h2s[k];
        float2 hB = h2s[k + 1];
        ai0 = fmaf(wiA, hA.x, ai0); ai1 = fmaf(wiA, hA.y, ai1);
        ai0 = fmaf(wiB, hB.x, ai0); ai1 = fmaf(wiB, hB.y, ai1);
        af0 = fmaf(wfA, hA.x, af0); af1 = fmaf(wfA, hA.y, af1);
        af0 = fmaf(wfB, hB.x, af0); af1 = fmaf(wfB, hB.y, af1);
        ag0 = fmaf(wgA, hA.x, ag0); ag1 = fmaf(wgA, hA.y, ag1);
        ag0 = fmaf(wgB, hB.x, ag0); ag1 = fmaf(wgB, hB.y, ag1);
        ao0 = fmaf(woA, hA.x, ao0); ao1 = fmaf(woA, hA.y, ao1);
        ao0 = fmaf(woB, hB.x, ao0); ao1 = fmaf(woB, hB.y, ao1);
      }
    } else {
      // 16 iters: reg-half (wreg[kk], k2=32q+kk) + stream-half (pws, k2=32q+16+kk).
      // 16 dot2 + 1 load per iter; reg dot2s hide the stream load latency.
      #pragma unroll
      for (int kk = 0; kk < 16; ++kk) {
        uint4 ws_ = pws[(size_t)kk * HID];
        uint2 hr  = h16q[32 * q + kk];
        ai0 = dot2f(wreg[kk].x, hr.x, ai0); ai1 = dot2f(wreg[kk].x, hr.y, ai1);
        af0 = dot2f(wreg[kk].y, hr.x, af0); af1 = dot2f(wreg[kk].y, hr.y, af1);
        ag0 = dot2f(wreg[kk].z, hr.x, ag0); ag1 = dot2f(wreg[kk].z, hr.y, ag1);
        ao0 = dot2f(wreg[kk].w, hr.x, ao0); ao1 = dot2f(wreg[kk].w, hr.y, ao1);
        uint2 hs = h16q[32 * q + 16 + kk];
        ai0 = dot2f(ws_.x, hs.x, ai0); ai1 = dot2f(ws_.x, hs.y, ai1);
        af0 = dot2f(ws_.y, hs.x, af0); af1 = dot2f(ws_.y, hs.y, af1);
        ag0 = dot2f(ws_.z, hs.x, ag0); ag1 = dot2f(ws_.z, hs.y, ag1);
        ao0 = dot2f(ws_.w, hs.x, ao0); ao1 = dot2f(ws_.w, hs.y, ao1);
      }
    }

    // ---- write partials [q][gate][row][u] (stride-4B in u -> conflict-free) ----
    part[q][0][0][u] = ai0; part[q][0][1][u] = ai1;
    part[q][1][0][u] = af0; part[q][1][1][u] = af1;
    part[q][2][0][u] = ag0; part[q][2][1][u] = ag1;
    part[q][3][0][u] = ao0; part[q][3][1][u] = ao1;

    __syncthreads();   // partials visible; all h reads of this step done

    // ---- reduce over 4 quarters + nonlinearity: thread (u, q<2) owns (row=q, u) ----
    if (q < 2) {
      float gi = part[0][0][q][u] + part[1][0][q][u] + part[2][0][q][u] + part[3][0][q][u];
      float gf = part[0][1][q][u] + part[1][1][q][u] + part[2][1][q][u] + part[3][1][q][u];
      float gg = part[0][2][q][u] + part[1][2][q][u] + part[2][2][q][u] + part[3][2][q][u];
      float go = part[0][3][q][u] + part[1][3][q][u] + part[2][3][q][u] + part[3][3][q][u];
      float iv = sigmoidf_(gi), fv = sigmoidf_(gf);
      float gv = tanhf_(gg),    ov = sigmoidf_(go);
      c_reg = fmaf(fv, c_reg, iv * gv);
      h_reg = ov * tanhf_(c_reg);
      ((float*)h2s)[u * 2 + q] = h_reg;           // fp32 h(step+1)
      h16[u >> 1][q][u & 1] = (_Float16)h_reg;    // fp16 shadow (dot2 operand)
    }

    __syncthreads();   // h(step+1) visible

    // ---- logits: waves 0..3 -> 4 (row, logit) combos, shuffle-reduce 64 lanes ----
    if (t < 256) {
      const int wv = t >> 6;        // 0..3
      const int lane = t & 63;
      const int r  = wv >> 1;       // row 0/1
      const int lg = wv & 1;
      float partial = 0.f;
      #pragma unroll
      for (int m = 0; m < 4; ++m) {
        int k = lane + 64 * m;
        float2 hv = h2s[k];
        float hval = r ? hv.y : hv.x;
        partial = fmaf(hval, wo[lg * HID + k], partial);
      }
      #pragma unroll
      for (int off = 32; off > 0; off >>= 1)
        partial += __shfl_down(partial, off, 64);
      if (lane == 0) {
        long row = (long)row0 + r;
        out[(row * T_STEPS + step) * 2 + lg] = partial + (lg ? b1 : b0);
      }
    }
  }

  // ---- final h_T, c_T (thread (u, q<2) owns (row=q, u); coalesced over u) ----
  if (q < 2) {
    const long HOFF = (long)B_ROWS * T_STEPS * 2;           // 524288
    const long COFF = HOFF + (long)B_ROWS * HID;            // 655360
    const long grow = (long)row0 + q;
    out[HOFF + grow * HID + u] = h_reg;
    out[COFF + grow * HID + u] = c_reg;
  }
}

extern "C" void kernel_launch(void* const* d_in, const int* in_sizes, int n_in,
                              void* d_out, int out_size, void* d_ws, size_t ws_size,
                              hipStream_t stream) {
  const float* hist = (const float*)d_in[0];
  const float* Wih  = (const float*)d_in[1];
  const float* Whh  = (const float*)d_in[2];
  const float* Wout = (const float*)d_in[3];
  const float* bout = (const float*)d_in[4];
  float* out = (float*)d_out;

  if (ws_size >= WS_BYTES_NEEDED) {
    uint4* PW2  = (uint4*)d_ws;
    float* PWih = (float*)((char*)d_ws + (size_t)PW2_ENTRIES * 16);
    // (32768 + 8192) / 256 = 160 blocks exactly
    prep_kernel<<<160, 256, 0, stream>>>(Wih, Whh, PW2, PWih);
    lstm_kernel<false><<<B_ROWS / 2, 1024, 0, stream>>>(
        hist, Wih, Whh, Wout, bout, PW2, (const float4*)PWih, out);
  } else {
    lstm_kernel<true><<<B_ROWS / 2, 1024, 0, stream>>>(
        hist, Wih, Whh, Wout, bout, nullptr, nullptr, out);
  }
}